// Round 13
// baseline (694.787 us; speedup 1.0000x reference)
//
#include <hip/hip_runtime.h>
#include <hip/hip_bf16.h>
#include <math.h>

#define N_TOK 4096
#define CDIM 1024
#define HDIM 2752
#define NEXP 8

typedef __bf16 bf16_t;
typedef __bf16 bf16x8 __attribute__((ext_vector_type(8)));
typedef float f32x4 __attribute__((ext_vector_type(4)));

__device__ __forceinline__ void gload_lds16(const void* g, void* l) {
  __builtin_amdgcn_global_load_lds(
      (const __attribute__((address_space(1))) unsigned int*)g,
      (__attribute__((address_space(3))) unsigned int*)l, 16, 0, 0);
}

// bijective XCD chunk swizzle (m204)
__device__ __forceinline__ int xcd_swz(int orig, int nwg) {
  int q = nwg >> 3, r = nwg & 7;
  int xcd = orig & 7, lin = orig >> 3;
  return (xcd < r ? xcd * (q + 1) : r * (q + 1) + (xcd - r) * q) + lin;
}

// ---------------- fused: f32->bf16 cast over 6 tensors + gating tail ----------------
struct CastG {
  const float* src[6];
  bf16_t* dst[6];
  int start[7];            // cumulative cast-block starts; 1024 floats per block
  const float* x;          // gating inputs
  const float* gw;
  int* top_i; float* top_w; float* probs_tok; bf16_t* xb;
};
__global__ void moe_cast_gate(CastG c) {
  const int b = blockIdx.x;
  if (b < c.start[6]) {
    // ---- cast segment ----
    int k = 0;
#pragma unroll
    for (int i = 0; i < 5; ++i) k += (b >= c.start[i + 1]);
    size_t i4 = (size_t)(b - c.start[k]) * 256 + threadIdx.x;  // float4 index
    float4 v = ((const float4*)c.src[k])[i4];
    union { bf16_t b4[4]; unsigned long long u; } pk;
    pk.b4[0] = (bf16_t)v.x; pk.b4[1] = (bf16_t)v.y;
    pk.b4[2] = (bf16_t)v.z; pk.b4[3] = (bf16_t)v.w;
    ((unsigned long long*)c.dst[k])[i4] = pk.u;
    return;
  }
  // ---- gating segment: 1024 blocks x 4 waves, one token per wave ----
  const int gb = b - c.start[6];
  const int wid = threadIdx.x >> 6, lane = threadIdx.x & 63;
  const int n = gb * 4 + wid;
  const float* xr = c.x + (size_t)n * CDIM;
  float xv[16];
  for (int j = 0; j < 16; j += 4)
    *(float4*)&xv[j] = *(const float4*)(xr + lane * 16 + j);
  {
    union { bf16_t bb[4]; unsigned long long u; } pk;
    unsigned long long* dst = (unsigned long long*)(c.xb + (size_t)n * CDIM + lane * 16);
    for (int j = 0; j < 16; j += 4) {
      pk.bb[0] = (bf16_t)xv[j]; pk.bb[1] = (bf16_t)xv[j+1];
      pk.bb[2] = (bf16_t)xv[j+2]; pk.bb[3] = (bf16_t)xv[j+3];
      dst[j >> 2] = pk.u;
    }
  }
  double part[NEXP];
  for (int e = 0; e < NEXP; ++e) {
    const float* gr = c.gw + e * CDIM + lane * 16;
    double s = 0.0;
    for (int j = 0; j < 16; j += 4) {
      float4 g = *(const float4*)(gr + j);
      s += (double)xv[j] * g.x + (double)xv[j+1] * g.y + (double)xv[j+2] * g.z + (double)xv[j+3] * g.w;
    }
    part[e] = s;
  }
  for (int off = 32; off; off >>= 1)
    for (int e = 0; e < NEXP; ++e) part[e] += __shfl_xor(part[e], off);
  if (lane == 0) {
    int i0 = 0; double l0 = part[0];
    for (int e = 1; e < NEXP; ++e) if (part[e] > l0) { l0 = part[e]; i0 = e; }
    int i1 = -1; double l1 = -1e300;
    for (int e = 0; e < NEXP; ++e) if (e != i0 && part[e] > l1) { l1 = part[e]; i1 = e; }
    double ed = exp(l1 - l0);
    float w0 = (float)(1.0 / (1.0 + ed));
    float w1 = (float)(ed / (1.0 + ed));
    c.top_i[2*n] = i0; c.top_i[2*n+1] = i1;
    c.top_w[2*n] = w0; c.top_w[2*n+1] = w1;
    double Z = 0.0, pe[NEXP];
    for (int e = 0; e < NEXP; ++e) { pe[e] = exp(part[e] - l0); Z += pe[e]; }
    for (int e = 0; e < NEXP; ++e) c.probs_tok[(size_t)n * NEXP + e] = (float)(pe[e] / Z);
  }
}

// ---------------- reduce16: per-block-range per-expert counts + prob partial sums ----------------
__global__ __launch_bounds__(256) void moe_reduce16(
    const float* __restrict__ probs_tok, const int* __restrict__ top_i,
    int* __restrict__ pcnt, float* __restrict__ psum) {
  const int b = blockIdx.x, t = threadIdx.x;
  const int wid = t >> 6, lane = t & 63;
  const int n = b * 256 + t;
  const int e0 = top_i[2*n], e1 = top_i[2*n + 1];
  float4 p0 = ((const float4*)(probs_tok + (size_t)n * NEXP))[0];
  float4 p1 = ((const float4*)(probs_tok + (size_t)n * NEXP))[1];
  float pv[8] = {p0.x, p0.y, p0.z, p0.w, p1.x, p1.y, p1.z, p1.w};
  __shared__ int lc[4][NEXP];
  __shared__ float ls[4][NEXP];
  for (int e = 0; e < NEXP; ++e) {
    int c = (e0 == e) + (e1 == e);
    float s = pv[e];
    for (int o = 32; o; o >>= 1) { c += __shfl_xor(c, o); s += __shfl_xor(s, o); }
    if (lane == 0) { lc[wid][e] = c; ls[wid][e] = s; }
  }
  __syncthreads();
  if (t < NEXP) {
    pcnt[b * NEXP + t] = lc[0][t] + lc[1][t] + lc[2][t] + lc[3][t];
    psum[b * NEXP + t] = ls[0][t] + ls[1][t] + ls[2][t] + ls[3][t];
  }
}

// ---------------- scatter16: deterministic positions, no global atomics ----------------
__global__ __launch_bounds__(256) void moe_scatter16(
    const int* __restrict__ top_i, const float* __restrict__ top_w,
    const int* __restrict__ pcnt, const float* __restrict__ psum,
    int* __restrict__ cnts_g, int* __restrict__ offs_g,
    int* __restrict__ rowlist, float* __restrict__ wlist,
    int* __restrict__ pair_pos, float* __restrict__ out_aux) {
  const int b = blockIdx.x, t = threadIdx.x;
  const int wid = t >> 6, lane = t & 63;
  __shared__ int tot_s[NEXP], pre_s[NEXP], offs_s[NEXP];
  __shared__ int wc[4][NEXP];
  if (t < NEXP) {
    int e = t, tot = 0, pre = 0;
    for (int bb = 0; bb < 16; ++bb) {
      int v = pcnt[bb * NEXP + e];
      pre += (bb < b) ? v : 0;
      tot += v;
    }
    tot_s[e] = tot; pre_s[e] = pre;
  }
  __syncthreads();
  if (t == 0) {
    int o = 0;
    for (int e = 0; e < NEXP; ++e) { offs_s[e] = o; o += tot_s[e]; }
    if (b == 0) {
      double aux = 0.0;
      for (int e = 0; e < NEXP; ++e) {
        float ps = 0.f;
        for (int bb = 0; bb < 16; ++bb) ps += psum[bb * NEXP + e];
        aux += (double)tot_s[e] * (double)ps;
        cnts_g[e] = tot_s[e]; offs_g[e] = offs_s[e];
      }
      out_aux[0] = (float)(0.01 * aux / ((double)N_TOK * (double)N_TOK));
    }
  }
  __syncthreads();
  const int n = b * 256 + t;
  const int e0 = top_i[2*n], e1 = top_i[2*n + 1];
  const float w0 = top_w[2*n], w1 = top_w[2*n + 1];
  for (int e = 0; e < NEXP; ++e) {
    unsigned long long m0 = __ballot(e0 == e);
    unsigned long long m1 = __ballot(e1 == e);
    if (lane == 0) wc[wid][e] = __popcll(m0) + __popcll(m1);
  }
  __syncthreads();
  const unsigned long long lt = ((unsigned long long)1 << lane) - 1;
  for (int e = 0; e < NEXP; ++e) {
    unsigned long long m0 = __ballot(e0 == e);
    unsigned long long m1 = __ballot(e1 == e);
    int wp = 0;
    for (int w = 0; w < wid; ++w) wp += wc[w][e];
    int base = offs_s[e] + pre_s[e] + wp;
    if (e0 == e) {
      int p = base + __popcll(m0 & lt);
      rowlist[p] = n; wlist[p] = w0; pair_pos[2*n] = p;
    }
    if (e1 == e) {
      int p = base + __popcll(m0) + __popcll(m1 & lt);
      rowlist[p] = n; wlist[p] = w1; pair_pos[2*n + 1] = p;
    }
  }
}

// ---------------- gate+up GEMM: BM=128, 64 h-cols, B = [Wg(64); Wu(64)] ----------------
// grid: x = n-panel (fastest -> gathered A rows stay L2-hot), y = m-block, z = expert/shared
__launch_bounds__(256)
__global__ void moe_gu(const bf16_t* __restrict__ xb,
                       const bf16_t* __restrict__ Wg_r, const bf16_t* __restrict__ Wu_r,
                       const bf16_t* __restrict__ Wg_s, const bf16_t* __restrict__ Wu_s,
                       bf16_t* __restrict__ hout,
                       const int* __restrict__ rowlist, const int* __restrict__ offs,
                       const int* __restrict__ cnts) {
  const int z = blockIdx.z;
  const bool routed = z < NEXP;
  int cnt, hbase, loff = 0;
  const bf16_t *Wg, *Wu;
  if (routed) {
    cnt = cnts[z]; loff = offs[z]; hbase = loff;
    if ((int)blockIdx.y * 128 >= cnt) return;
    Wg = Wg_r + (size_t)z * HDIM * CDIM;
    Wu = Wu_r + (size_t)z * HDIM * CDIM;
  } else {
    cnt = N_TOK; hbase = 2 * N_TOK;   // shared h rows at [8192, 12288)
    Wg = Wg_s; Wu = Wu_s;
  }
  const int m0 = blockIdx.y * 128, n0 = blockIdx.x * 64;

  __shared__ alignas(16) bf16_t lA[128 * 64];   // 16 KB
  __shared__ alignas(16) bf16_t lB[128 * 64];   // 16 KB: rows 0-63 = Wg, 64-127 = Wu

  const int tid = threadIdx.x, wid = tid >> 6, lane = tid & 63;
  const int r8 = lane >> 3, c8 = lane & 7;
  const int fr = lane & 15, hi = lane >> 4;

  const bf16_t* gA[4];
  for (int i = 0; i < 4; ++i) {
    int r = wid * 32 + i * 8 + r8;
    int tok;
    if (routed) { int mm = m0 + r < cnt ? m0 + r : cnt - 1; tok = rowlist[loff + mm]; }
    else tok = m0 + r;
    gA[i] = xb + (size_t)tok * CDIM + c8 * 8;
  }
  const bf16_t* gB[4];
  for (int i = 0; i < 4; ++i) {
    int br = wid * 32 + i * 8 + r8;
    gB[i] = (br < 64 ? Wg + (size_t)(n0 + br) * CDIM
                     : Wu + (size_t)(n0 + br - 64) * CDIM) + c8 * 8;
  }

  f32x4 accG[2][4] = {}; f32x4 accU[2][4] = {};

  for (int kt = 0; kt < CDIM / 64; ++kt) {
    if (kt) __syncthreads();
    for (int i = 0; i < 4; ++i) gload_lds16(gA[i] + kt * 64, lA + (wid * 32 + i * 8) * 64);
    for (int i = 0; i < 4; ++i) gload_lds16(gB[i] + kt * 64, lB + (wid * 32 + i * 8) * 64);
    __syncthreads();
    for (int kk = 0; kk < 2; ++kk) {
      const int kb = kk * 32 + hi * 8;
      bf16x8 a[2], bg[4], bu[4];
      for (int i = 0; i < 2; ++i) a[i] = *(const bf16x8*)(lA + (wid * 32 + i * 16 + fr) * 64 + kb);
      for (int j = 0; j < 4; ++j) {
        bg[j] = *(const bf16x8*)(lB + (j * 16 + fr) * 64 + kb);
        bu[j] = *(const bf16x8*)(lB + (64 + j * 16 + fr) * 64 + kb);
      }
      for (int i = 0; i < 2; ++i)
        for (int j = 0; j < 4; ++j) {
          accG[i][j] = __builtin_amdgcn_mfma_f32_16x16x32_bf16(a[i], bg[j], accG[i][j], 0, 0, 0);
          accU[i][j] = __builtin_amdgcn_mfma_f32_16x16x32_bf16(a[i], bu[j], accU[i][j], 0, 0, 0);
        }
    }
  }
  // SwiGLU epilogue -> bf16 h, coalesced via per-wave LDS transpose.
  // Each wave reuses ONLY its own 32-row lA band (written/read by itself) -> no barrier.
  {
    bf16_t* myb = lA + wid * 32 * 64;
    for (int i = 0; i < 2; ++i)
      for (int j = 0; j < 4; ++j)
        for (int r = 0; r < 4; ++r) {
          int lrow = i * 16 + hi * 4 + r;
          float g = accG[i][j][r], u = accU[i][j][r];
          float hv = (g / (1.f + __expf(-g))) * u;
          myb[lrow * 64 + j * 16 + fr] = (bf16_t)hv;
        }
    asm volatile("s_waitcnt lgkmcnt(0)" ::: "memory");
    __builtin_amdgcn_sched_barrier(0);
    for (int round = 0; round < 4; ++round) {
      int lrow = round * 8 + (lane >> 3);
      int grow = m0 + wid * 32 + lrow;
      if (routed && grow >= cnt) continue;
      bf16x8 v = *(const bf16x8*)(myb + lrow * 64 + (lane & 7) * 8);
      *(bf16x8*)(hout + (size_t)(hbase + grow) * HDIM + n0 + (lane & 7) * 8) = v;
    }
  }
}

// ---------------- down GEMM: BM=128, BN=128, BK=64, 2x2 waves ----------------
// grid: flattened 8n x 32m, XCD chunks, then 2m x 4n SUPERTILES inside each chunk:
// L2 working set = 4 Wd panels (2.8 MB) + 2 h chunks (1.4 MB) -> both operands L2-hot.
// Plain-store epilogue: routed -> eo[pos]*w, shared -> out.
__launch_bounds__(256)
__global__ void moe_down(const bf16_t* __restrict__ hin, const bf16_t* __restrict__ Wd_r,
                         const bf16_t* __restrict__ Wd_s,
                         float* __restrict__ outp, float* __restrict__ eo,
                         const float* __restrict__ wlist,
                         const int* __restrict__ offs, const int* __restrict__ cnts) {
  const int z = blockIdx.z;
  const bool routed = z < NEXP;
  const int wg = xcd_swz(blockIdx.x, (CDIM / 128) * (N_TOK / 128));
  const int st = wg >> 3, wi = wg & 7;       // supertile of 8 blocks = 2m x 4n
  const int ym = (st & 15) * 2 + (wi >> 2);
  const int xn = (st >> 4) * 4 + (wi & 3);
  int cnt, hbase;
  const bf16_t* Wd;
  if (routed) {
    cnt = cnts[z]; hbase = offs[z];
    if (ym * 128 >= cnt) return;
    Wd = Wd_r + (size_t)z * CDIM * HDIM;
  } else {
    cnt = N_TOK; hbase = 2 * N_TOK;
    Wd = Wd_s;
  }
  const int m0 = ym * 128, n0 = xn * 128;

  __shared__ alignas(16) bf16_t lA[128 * 64];   // 16 KB
  __shared__ alignas(16) bf16_t lB[128 * 64];   // 16 KB

  const int tid = threadIdx.x, wid = tid >> 6, lane = tid & 63;
  const int wm = wid >> 1, wn = wid & 1;
  const int r8 = lane >> 3, c8 = lane & 7;
  const int fr = lane & 15, hi = lane >> 4;

  const bf16_t* gA[4];
  for (int i = 0; i < 4; ++i) {
    int r = wid * 32 + i * 8 + r8;
    int mm = (routed && m0 + r >= cnt) ? cnt - 1 : m0 + r;
    gA[i] = hin + (size_t)(hbase + mm) * HDIM + c8 * 8;
  }
  const bf16_t* gB[4];
  for (int i = 0; i < 4; ++i) {
    int br = wid * 32 + i * 8 + r8;
    gB[i] = Wd + (size_t)(n0 + br) * HDIM + c8 * 8;
  }

  f32x4 acc[4][4] = {};

  for (int kt = 0; kt < HDIM / 64; ++kt) {
    if (kt) __syncthreads();
    for (int i = 0; i < 4; ++i) gload_lds16(gA[i] + kt * 64, lA + (wid * 32 + i * 8) * 64);
    for (int i = 0; i < 4; ++i) gload_lds16(gB[i] + kt * 64, lB + (wid * 32 + i * 8) * 64);
    __syncthreads();
    for (int kk = 0; kk < 2; ++kk) {
      const int kb = kk * 32 + hi * 8;
      bf16x8 a[4], b[4];
      for (int i = 0; i < 4; ++i) a[i] = *(const bf16x8*)(lA + (wm * 64 + i * 16 + fr) * 64 + kb);
      for (int j = 0; j < 4; ++j) b[j] = *(const bf16x8*)(lB + (wn * 64 + j * 16 + fr) * 64 + kb);
      for (int i = 0; i < 4; ++i)
        for (int j = 0; j < 4; ++j)
          acc[i][j] = __builtin_amdgcn_mfma_f32_16x16x32_bf16(a[i], b[j], acc[i][j], 0, 0, 0);
    }
  }
  for (int i = 0; i < 4; ++i)
    for (int j = 0; j < 4; ++j)
      for (int r = 0; r < 4; ++r) {
        int lm = wm * 64 + i * 16 + hi * 4 + r;
        if (routed && m0 + lm >= cnt) continue;
        float v = acc[i][j][r];
        int col = n0 + wn * 64 + j * 16 + fr;
        if (routed) {
          int pos = hbase + m0 + lm;
          eo[(size_t)pos * CDIM + col] = v * wlist[pos];
        } else {
          outp[(size_t)(m0 + lm) * CDIM + col] = v;
        }
      }
}

// ---------------- combine: out = shared + w0*E0 + w1*E1 (weights pre-applied) ----------------
__global__ void moe_combine(float* __restrict__ outp, const float* __restrict__ eo,
                            const int* __restrict__ pair_pos) {
  size_t i4 = (size_t)blockIdx.x * 256 + threadIdx.x;  // float4 index
  int n = (int)(i4 >> 8);
  int c4 = (int)(i4 & 255);
  int p0 = pair_pos[2*n], p1 = pair_pos[2*n + 1];
  const float4* eo4 = (const float4*)eo;
  float4 a = ((const float4*)outp)[i4];
  float4 b = eo4[(size_t)p0 * 256 + c4];
  float4 c = eo4[(size_t)p1 * 256 + c4];
  float4 r;
  r.x = a.x + b.x + c.x; r.y = a.y + b.y + c.y;
  r.z = a.z + b.z + c.z; r.w = a.w + b.w + c.w;
  ((float4*)outp)[i4] = r;
}

extern "C" void kernel_launch(void* const* d_in, const int* in_sizes, int n_in,
                              void* d_out, int out_size, void* d_ws, size_t ws_size,
                              hipStream_t stream) {
  const float* x   = (const float*)d_in[0];
  const float* gw  = (const float*)d_in[1];
  const float* egw = (const float*)d_in[2];
  const float* euw = (const float*)d_in[3];
  const float* edw = (const float*)d_in[4];
  const float* sgw = (const float*)d_in[5];
  const float* suw = (const float*)d_in[6];
  const float* sdw = (const float*)d_in[7];
  float* out = (float*)d_out;

  char* ws = (char*)d_ws;
  size_t off = 0;
  auto alloc = [&](size_t bytes) -> void* {
    void* p = ws + off; off = (off + bytes + 255) & ~(size_t)255; return p;
  };
  const size_t EW = (size_t)NEXP * HDIM * CDIM;   // 22,544,384
  const size_t SW = (size_t)HDIM * CDIM;          // 2,818,048
  bf16_t* xb    = (bf16_t*)alloc((size_t)N_TOK * CDIM * 2);
  bf16_t* egw_b = (bf16_t*)alloc(EW * 2);
  bf16_t* euw_b = (bf16_t*)alloc(EW * 2);
  bf16_t* edw_b = (bf16_t*)alloc(EW * 2);
  bf16_t* sgw_b = (bf16_t*)alloc(SW * 2);
  bf16_t* suw_b = (bf16_t*)alloc(SW * 2);
  bf16_t* sdw_b = (bf16_t*)alloc(SW * 2);
  bf16_t* h     = (bf16_t*)alloc((size_t)(3 * N_TOK + 256) * HDIM * 2);
  float*  eo    = (float*)alloc((size_t)2 * N_TOK * CDIM * 4);
  int*    ctrl  = (int*)alloc(256);
  int* cnts = ctrl; int* offs = ctrl + 8;
  int*   top_i    = (int*)alloc((size_t)N_TOK * 2 * 4);
  float* top_w    = (float*)alloc((size_t)N_TOK * 2 * 4);
  int*   pair_pos = (int*)alloc((size_t)N_TOK * 2 * 4);
  int*   rowlist  = (int*)alloc((size_t)2 * N_TOK * 4);
  float* wlist    = (float*)alloc((size_t)2 * N_TOK * 4);
  float* probs_tok = (float*)alloc((size_t)N_TOK * NEXP * 4);
  int*   pcnt     = (int*)alloc(16 * NEXP * 4);
  float* psum     = (float*)alloc(16 * NEXP * 4);

  // fused weight precast (6 tensors) + gating, one launch
  CastG cg;
  cg.src[0] = egw; cg.dst[0] = egw_b;
  cg.src[1] = euw; cg.dst[1] = euw_b;
  cg.src[2] = edw; cg.dst[2] = edw_b;
  cg.src[3] = sgw; cg.dst[3] = sgw_b;
  cg.src[4] = suw; cg.dst[4] = suw_b;
  cg.src[5] = sdw; cg.dst[5] = sdw_b;
  int ew_blk = (int)(EW / 1024), sw_blk = (int)(SW / 1024);
  cg.start[0] = 0;
  cg.start[1] = ew_blk;     cg.start[2] = 2 * ew_blk; cg.start[3] = 3 * ew_blk;
  cg.start[4] = 3 * ew_blk + sw_blk;
  cg.start[5] = 3 * ew_blk + 2 * sw_blk;
  cg.start[6] = 3 * ew_blk + 3 * sw_blk;
  cg.x = x; cg.gw = gw;
  cg.top_i = top_i; cg.top_w = top_w; cg.probs_tok = probs_tok; cg.xb = xb;
  moe_cast_gate<<<cg.start[6] + N_TOK / 4, 256, 0, stream>>>(cg);

  // parallel control: 16-block reduce, then 16-block deterministic scatter
  moe_reduce16<<<16, 256, 0, stream>>>(probs_tok, top_i, pcnt, psum);
  moe_scatter16<<<16, 256, 0, stream>>>(top_i, top_w, pcnt, psum, cnts, offs,
                                        rowlist, wlist, pair_pos,
                                        out + (size_t)N_TOK * CDIM);

  // gate+up: x = n-panel (43, fastest), y = m-block (32), z = 8 routed + 1 shared
  moe_gu<<<dim3(HDIM / 64, N_TOK / 128, NEXP + 1), 256, 0, stream>>>(
      xb, egw_b, euw_b, sgw_b, suw_b, h, rowlist, offs, cnts);
  // down: flattened grid, XCD chunks + 2x4 supertiles; routed -> eo, shared -> out
  moe_down<<<dim3((CDIM / 128) * (N_TOK / 128), 1, NEXP + 1), 256, 0, stream>>>(
      h, edw_b, sdw_b, out, eo, wlist, offs, cnts);
  // combine: out = shared + routed pair
  moe_combine<<<4096, 256, 0, stream>>>(out, eo, pair_pos);
}

// Round 14
// 474.946 us; speedup vs baseline: 1.4629x; 1.4629x over previous
//
#include <hip/hip_runtime.h>
#include <hip/hip_bf16.h>
#include <math.h>

#define N_TOK 4096
#define CDIM 1024
#define HDIM 2752
#define NEXP 8

typedef __bf16 bf16_t;
typedef __bf16 bf16x8 __attribute__((ext_vector_type(8)));
typedef float f32x4 __attribute__((ext_vector_type(4)));

__device__ __forceinline__ void gload_lds16(const void* g, void* l) {
  __builtin_amdgcn_global_load_lds(
      (const __attribute__((address_space(1))) unsigned int*)g,
      (__attribute__((address_space(3))) unsigned int*)l, 16, 0, 0);
}

// bijective XCD chunk swizzle (m204)
__device__ __forceinline__ int xcd_swz(int orig, int nwg) {
  int q = nwg >> 3, r = nwg & 7;
  int xcd = orig & 7, lin = orig >> 3;
  return (xcd < r ? xcd * (q + 1) : r * (q + 1) + (xcd - r) * q) + lin;
}

// ---------------- fused: f32->bf16 cast over 4 gu-side tensors + gating tail ----------------
struct CastG {
  const float* src[4];
  bf16_t* dst[4];
  int start[5];            // cumulative cast-block starts; 1024 floats per block
  const float* x;          // gating inputs
  const float* gw;
  int* top_i; float* top_w; float* probs_tok; bf16_t* xb;
};
__global__ void moe_cast_gate(CastG c) {
  const int b = blockIdx.x;
  if (b < c.start[4]) {
    // ---- cast segment ----
    int k = 0;
#pragma unroll
    for (int i = 0; i < 3; ++i) k += (b >= c.start[i + 1]);
    size_t i4 = (size_t)(b - c.start[k]) * 256 + threadIdx.x;  // float4 index
    float4 v = ((const float4*)c.src[k])[i4];
    union { bf16_t b4[4]; unsigned long long u; } pk;
    pk.b4[0] = (bf16_t)v.x; pk.b4[1] = (bf16_t)v.y;
    pk.b4[2] = (bf16_t)v.z; pk.b4[3] = (bf16_t)v.w;
    ((unsigned long long*)c.dst[k])[i4] = pk.u;
    return;
  }
  // ---- gating segment: 1024 blocks x 4 waves, one token per wave ----
  const int gb = b - c.start[4];
  const int wid = threadIdx.x >> 6, lane = threadIdx.x & 63;
  const int n = gb * 4 + wid;
  const float* xr = c.x + (size_t)n * CDIM;
  float xv[16];
  for (int j = 0; j < 16; j += 4)
    *(float4*)&xv[j] = *(const float4*)(xr + lane * 16 + j);
  {
    union { bf16_t bb[4]; unsigned long long u; } pk;
    unsigned long long* dst = (unsigned long long*)(c.xb + (size_t)n * CDIM + lane * 16);
    for (int j = 0; j < 16; j += 4) {
      pk.bb[0] = (bf16_t)xv[j]; pk.bb[1] = (bf16_t)xv[j+1];
      pk.bb[2] = (bf16_t)xv[j+2]; pk.bb[3] = (bf16_t)xv[j+3];
      dst[j >> 2] = pk.u;
    }
  }
  double part[NEXP];
  for (int e = 0; e < NEXP; ++e) {
    const float* gr = c.gw + e * CDIM + lane * 16;
    double s = 0.0;
    for (int j = 0; j < 16; j += 4) {
      float4 g = *(const float4*)(gr + j);
      s += (double)xv[j] * g.x + (double)xv[j+1] * g.y + (double)xv[j+2] * g.z + (double)xv[j+3] * g.w;
    }
    part[e] = s;
  }
  for (int off = 32; off; off >>= 1)
    for (int e = 0; e < NEXP; ++e) part[e] += __shfl_xor(part[e], off);
  if (lane == 0) {
    int i0 = 0; double l0 = part[0];
    for (int e = 1; e < NEXP; ++e) if (part[e] > l0) { l0 = part[e]; i0 = e; }
    int i1 = -1; double l1 = -1e300;
    for (int e = 0; e < NEXP; ++e) if (e != i0 && part[e] > l1) { l1 = part[e]; i1 = e; }
    double ed = exp(l1 - l0);
    float w0 = (float)(1.0 / (1.0 + ed));
    float w1 = (float)(ed / (1.0 + ed));
    c.top_i[2*n] = i0; c.top_i[2*n+1] = i1;
    c.top_w[2*n] = w0; c.top_w[2*n+1] = w1;
    double Z = 0.0, pe[NEXP];
    for (int e = 0; e < NEXP; ++e) { pe[e] = exp(part[e] - l0); Z += pe[e]; }
    for (int e = 0; e < NEXP; ++e) c.probs_tok[(size_t)n * NEXP + e] = (float)(pe[e] / Z);
  }
}

// ---------------- reduce16: per-block-range per-expert counts + prob partial sums ----------------
__global__ __launch_bounds__(256) void moe_reduce16(
    const float* __restrict__ probs_tok, const int* __restrict__ top_i,
    int* __restrict__ pcnt, float* __restrict__ psum) {
  const int b = blockIdx.x, t = threadIdx.x;
  const int wid = t >> 6, lane = t & 63;
  const int n = b * 256 + t;
  const int e0 = top_i[2*n], e1 = top_i[2*n + 1];
  float4 p0 = ((const float4*)(probs_tok + (size_t)n * NEXP))[0];
  float4 p1 = ((const float4*)(probs_tok + (size_t)n * NEXP))[1];
  float pv[8] = {p0.x, p0.y, p0.z, p0.w, p1.x, p1.y, p1.z, p1.w};
  __shared__ int lc[4][NEXP];
  __shared__ float ls[4][NEXP];
  for (int e = 0; e < NEXP; ++e) {
    int c = (e0 == e) + (e1 == e);
    float s = pv[e];
    for (int o = 32; o; o >>= 1) { c += __shfl_xor(c, o); s += __shfl_xor(s, o); }
    if (lane == 0) { lc[wid][e] = c; ls[wid][e] = s; }
  }
  __syncthreads();
  if (t < NEXP) {
    pcnt[b * NEXP + t] = lc[0][t] + lc[1][t] + lc[2][t] + lc[3][t];
    psum[b * NEXP + t] = ls[0][t] + ls[1][t] + ls[2][t] + ls[3][t];
  }
}

// ---------------- scatter16: deterministic positions, no global atomics ----------------
__global__ __launch_bounds__(256) void moe_scatter16(
    const int* __restrict__ top_i, const float* __restrict__ top_w,
    const int* __restrict__ pcnt, const float* __restrict__ psum,
    int* __restrict__ cnts_g, int* __restrict__ offs_g,
    int* __restrict__ rowlist, float* __restrict__ wlist,
    int* __restrict__ pair_pos, float* __restrict__ out_aux) {
  const int b = blockIdx.x, t = threadIdx.x;
  const int wid = t >> 6, lane = t & 63;
  __shared__ int tot_s[NEXP], pre_s[NEXP], offs_s[NEXP];
  __shared__ int wc[4][NEXP];
  if (t < NEXP) {
    int e = t, tot = 0, pre = 0;
    for (int bb = 0; bb < 16; ++bb) {
      int v = pcnt[bb * NEXP + e];
      pre += (bb < b) ? v : 0;
      tot += v;
    }
    tot_s[e] = tot; pre_s[e] = pre;
  }
  __syncthreads();
  if (t == 0) {
    int o = 0;
    for (int e = 0; e < NEXP; ++e) { offs_s[e] = o; o += tot_s[e]; }
    if (b == 0) {
      double aux = 0.0;
      for (int e = 0; e < NEXP; ++e) {
        float ps = 0.f;
        for (int bb = 0; bb < 16; ++bb) ps += psum[bb * NEXP + e];
        aux += (double)tot_s[e] * (double)ps;
        cnts_g[e] = tot_s[e]; offs_g[e] = offs_s[e];
      }
      out_aux[0] = (float)(0.01 * aux / ((double)N_TOK * (double)N_TOK));
    }
  }
  __syncthreads();
  const int n = b * 256 + t;
  const int e0 = top_i[2*n], e1 = top_i[2*n + 1];
  const float w0 = top_w[2*n], w1 = top_w[2*n + 1];
  for (int e = 0; e < NEXP; ++e) {
    unsigned long long m0 = __ballot(e0 == e);
    unsigned long long m1 = __ballot(e1 == e);
    if (lane == 0) wc[wid][e] = __popcll(m0) + __popcll(m1);
  }
  __syncthreads();
  const unsigned long long lt = ((unsigned long long)1 << lane) - 1;
  for (int e = 0; e < NEXP; ++e) {
    unsigned long long m0 = __ballot(e0 == e);
    unsigned long long m1 = __ballot(e1 == e);
    int wp = 0;
    for (int w = 0; w < wid; ++w) wp += wc[w][e];
    int base = offs_s[e] + pre_s[e] + wp;
    if (e0 == e) {
      int p = base + __popcll(m0 & lt);
      rowlist[p] = n; wlist[p] = w0; pair_pos[2*n] = p;
    }
    if (e1 == e) {
      int p = base + __popcll(m0) + __popcll(m1 & lt);
      rowlist[p] = n; wlist[p] = w1; pair_pos[2*n + 1] = p;
    }
  }
}

// ---------------- gate+up GEMM + piggybacked down-weight cast (z == NEXP+1) ----------------
// grid: x = n-panel (fastest -> gathered A rows stay L2-hot), y = m-block,
//       z = expert (0..7) / shared (8) / down-weight cast slice (9, overlaps with GEMM)
__launch_bounds__(256)
__global__ void moe_gu(const bf16_t* __restrict__ xb,
                       const bf16_t* __restrict__ Wg_r, const bf16_t* __restrict__ Wu_r,
                       const bf16_t* __restrict__ Wg_s, const bf16_t* __restrict__ Wu_s,
                       bf16_t* __restrict__ hout,
                       const int* __restrict__ rowlist, const int* __restrict__ offs,
                       const int* __restrict__ cnts,
                       const float* __restrict__ edw_f, const float* __restrict__ sdw_f,
                       bf16_t* __restrict__ edw_b, bf16_t* __restrict__ sdw_b) {
  const int z = blockIdx.z;
  if (z == NEXP + 1) {
    // ---- down-weight cast slice: 1376 blocks grid-stride over edw|sdw (f32->bf16) ----
    const int lb = blockIdx.x + (HDIM / 64) * blockIdx.y;          // 0..1375
    const size_t E4 = (size_t)NEXP * HDIM * CDIM / 4;              // 5,636,096
    const size_t S4 = (size_t)HDIM * CDIM / 4;                     // 704,512
    const size_t tot4 = E4 + S4;
    const size_t stride = (size_t)(HDIM / 64) * (N_TOK / 128) * 256;  // 352,256
    for (size_t i4 = (size_t)lb * 256 + threadIdx.x; i4 < tot4; i4 += stride) {
      float4 v; unsigned long long* d;
      if (i4 < E4) { v = ((const float4*)edw_f)[i4]; d = (unsigned long long*)edw_b + i4; }
      else { size_t j = i4 - E4; v = ((const float4*)sdw_f)[j]; d = (unsigned long long*)sdw_b + j; }
      union { bf16_t b4[4]; unsigned long long u; } pk;
      pk.b4[0] = (bf16_t)v.x; pk.b4[1] = (bf16_t)v.y;
      pk.b4[2] = (bf16_t)v.z; pk.b4[3] = (bf16_t)v.w;
      *d = pk.u;
    }
    return;
  }
  const bool routed = z < NEXP;
  int cnt, hbase, loff = 0;
  const bf16_t *Wg, *Wu;
  if (routed) {
    cnt = cnts[z]; loff = offs[z]; hbase = loff;
    if ((int)blockIdx.y * 128 >= cnt) return;
    Wg = Wg_r + (size_t)z * HDIM * CDIM;
    Wu = Wu_r + (size_t)z * HDIM * CDIM;
  } else {
    cnt = N_TOK; hbase = 2 * N_TOK;   // shared h rows at [8192, 12288)
    Wg = Wg_s; Wu = Wu_s;
  }
  const int m0 = blockIdx.y * 128, n0 = blockIdx.x * 64;

  __shared__ alignas(16) bf16_t lA[128 * 64];   // 16 KB
  __shared__ alignas(16) bf16_t lB[128 * 64];   // 16 KB: rows 0-63 = Wg, 64-127 = Wu

  const int tid = threadIdx.x, wid = tid >> 6, lane = tid & 63;
  const int r8 = lane >> 3, c8 = lane & 7;
  const int fr = lane & 15, hi = lane >> 4;

  const bf16_t* gA[4];
  for (int i = 0; i < 4; ++i) {
    int r = wid * 32 + i * 8 + r8;
    int tok;
    if (routed) { int mm = m0 + r < cnt ? m0 + r : cnt - 1; tok = rowlist[loff + mm]; }
    else tok = m0 + r;
    gA[i] = xb + (size_t)tok * CDIM + c8 * 8;
  }
  const bf16_t* gB[4];
  for (int i = 0; i < 4; ++i) {
    int br = wid * 32 + i * 8 + r8;
    gB[i] = (br < 64 ? Wg + (size_t)(n0 + br) * CDIM
                     : Wu + (size_t)(n0 + br - 64) * CDIM) + c8 * 8;
  }

  f32x4 accG[2][4] = {}; f32x4 accU[2][4] = {};

  for (int kt = 0; kt < CDIM / 64; ++kt) {
    if (kt) __syncthreads();
    for (int i = 0; i < 4; ++i) gload_lds16(gA[i] + kt * 64, lA + (wid * 32 + i * 8) * 64);
    for (int i = 0; i < 4; ++i) gload_lds16(gB[i] + kt * 64, lB + (wid * 32 + i * 8) * 64);
    __syncthreads();
    for (int kk = 0; kk < 2; ++kk) {
      const int kb = kk * 32 + hi * 8;
      bf16x8 a[2], bg[4], bu[4];
      for (int i = 0; i < 2; ++i) a[i] = *(const bf16x8*)(lA + (wid * 32 + i * 16 + fr) * 64 + kb);
      for (int j = 0; j < 4; ++j) {
        bg[j] = *(const bf16x8*)(lB + (j * 16 + fr) * 64 + kb);
        bu[j] = *(const bf16x8*)(lB + (64 + j * 16 + fr) * 64 + kb);
      }
      for (int i = 0; i < 2; ++i)
        for (int j = 0; j < 4; ++j) {
          accG[i][j] = __builtin_amdgcn_mfma_f32_16x16x32_bf16(a[i], bg[j], accG[i][j], 0, 0, 0);
          accU[i][j] = __builtin_amdgcn_mfma_f32_16x16x32_bf16(a[i], bu[j], accU[i][j], 0, 0, 0);
        }
    }
  }
  // SwiGLU epilogue -> bf16 h, coalesced via per-wave LDS transpose (wave-private band).
  {
    bf16_t* myb = lA + wid * 32 * 64;
    for (int i = 0; i < 2; ++i)
      for (int j = 0; j < 4; ++j)
        for (int r = 0; r < 4; ++r) {
          int lrow = i * 16 + hi * 4 + r;
          float g = accG[i][j][r], u = accU[i][j][r];
          float hv = (g / (1.f + __expf(-g))) * u;
          myb[lrow * 64 + j * 16 + fr] = (bf16_t)hv;
        }
    asm volatile("s_waitcnt lgkmcnt(0)" ::: "memory");
    __builtin_amdgcn_sched_barrier(0);
    for (int round = 0; round < 4; ++round) {
      int lrow = round * 8 + (lane >> 3);
      int grow = m0 + wid * 32 + lrow;
      if (routed && grow >= cnt) continue;
      bf16x8 v = *(const bf16x8*)(myb + lrow * 64 + (lane & 7) * 8);
      *(bf16x8*)(hout + (size_t)(hbase + grow) * HDIM + n0 + (lane & 7) * 8) = v;
    }
  }
}

// ---------------- down GEMM: BM=128, BN=128, BK=64, 2x2 waves (R12-exact) ----------------
// grid: flattened 8n x 32m, m FASTEST + XCD chunk swizzle. Plain-store epilogue:
// routed -> eo[pos]*w, shared -> out.
__launch_bounds__(256)
__global__ void moe_down(const bf16_t* __restrict__ hin, const bf16_t* __restrict__ Wd_r,
                         const bf16_t* __restrict__ Wd_s,
                         float* __restrict__ outp, float* __restrict__ eo,
                         const float* __restrict__ wlist,
                         const int* __restrict__ offs, const int* __restrict__ cnts) {
  const int z = blockIdx.z;
  const bool routed = z < NEXP;
  const int wg = xcd_swz(blockIdx.x, (CDIM / 128) * (N_TOK / 128));
  const int ym = wg & 31, xn = wg >> 5;      // m-block fastest
  int cnt, hbase;
  const bf16_t* Wd;
  if (routed) {
    cnt = cnts[z]; hbase = offs[z];
    if (ym * 128 >= cnt) return;
    Wd = Wd_r + (size_t)z * CDIM * HDIM;
  } else {
    cnt = N_TOK; hbase = 2 * N_TOK;
    Wd = Wd_s;
  }
  const int m0 = ym * 128, n0 = xn * 128;

  __shared__ alignas(16) bf16_t lA[128 * 64];   // 16 KB
  __shared__ alignas(16) bf16_t lB[128 * 64];   // 16 KB

  const int tid = threadIdx.x, wid = tid >> 6, lane = tid & 63;
  const int wm = wid >> 1, wn = wid & 1;
  const int r8 = lane >> 3, c8 = lane & 7;
  const int fr = lane & 15, hi = lane >> 4;

  const bf16_t* gA[4];
  for (int i = 0; i < 4; ++i) {
    int r = wid * 32 + i * 8 + r8;
    int mm = (routed && m0 + r >= cnt) ? cnt - 1 : m0 + r;
    gA[i] = hin + (size_t)(hbase + mm) * HDIM + c8 * 8;
  }
  const bf16_t* gB[4];
  for (int i = 0; i < 4; ++i) {
    int br = wid * 32 + i * 8 + r8;
    gB[i] = Wd + (size_t)(n0 + br) * HDIM + c8 * 8;
  }

  f32x4 acc[4][4] = {};

  for (int kt = 0; kt < HDIM / 64; ++kt) {
    if (kt) __syncthreads();
    for (int i = 0; i < 4; ++i) gload_lds16(gA[i] + kt * 64, lA + (wid * 32 + i * 8) * 64);
    for (int i = 0; i < 4; ++i) gload_lds16(gB[i] + kt * 64, lB + (wid * 32 + i * 8) * 64);
    __syncthreads();
    for (int kk = 0; kk < 2; ++kk) {
      const int kb = kk * 32 + hi * 8;
      bf16x8 a[4], b[4];
      for (int i = 0; i < 4; ++i) a[i] = *(const bf16x8*)(lA + (wm * 64 + i * 16 + fr) * 64 + kb);
      for (int j = 0; j < 4; ++j) b[j] = *(const bf16x8*)(lB + (wn * 64 + j * 16 + fr) * 64 + kb);
      for (int i = 0; i < 4; ++i)
        for (int j = 0; j < 4; ++j)
          acc[i][j] = __builtin_amdgcn_mfma_f32_16x16x32_bf16(a[i], b[j], acc[i][j], 0, 0, 0);
    }
  }
  for (int i = 0; i < 4; ++i)
    for (int j = 0; j < 4; ++j)
      for (int r = 0; r < 4; ++r) {
        int lm = wm * 64 + i * 16 + hi * 4 + r;
        if (routed && m0 + lm >= cnt) continue;
        float v = acc[i][j][r];
        int col = n0 + wn * 64 + j * 16 + fr;
        if (routed) {
          int pos = hbase + m0 + lm;
          eo[(size_t)pos * CDIM + col] = v * wlist[pos];
        } else {
          outp[(size_t)(m0 + lm) * CDIM + col] = v;
        }
      }
}

// ---------------- combine: out = shared + w0*E0 + w1*E1 (weights pre-applied) ----------------
__global__ void moe_combine(float* __restrict__ outp, const float* __restrict__ eo,
                            const int* __restrict__ pair_pos) {
  size_t i4 = (size_t)blockIdx.x * 256 + threadIdx.x;  // float4 index
  int n = (int)(i4 >> 8);
  int c4 = (int)(i4 & 255);
  int p0 = pair_pos[2*n], p1 = pair_pos[2*n + 1];
  const float4* eo4 = (const float4*)eo;
  float4 a = ((const float4*)outp)[i4];
  float4 b = eo4[(size_t)p0 * 256 + c4];
  float4 c = eo4[(size_t)p1 * 256 + c4];
  float4 r;
  r.x = a.x + b.x + c.x; r.y = a.y + b.y + c.y;
  r.z = a.z + b.z + c.z; r.w = a.w + b.w + c.w;
  ((float4*)outp)[i4] = r;
}

extern "C" void kernel_launch(void* const* d_in, const int* in_sizes, int n_in,
                              void* d_out, int out_size, void* d_ws, size_t ws_size,
                              hipStream_t stream) {
  const float* x   = (const float*)d_in[0];
  const float* gw  = (const float*)d_in[1];
  const float* egw = (const float*)d_in[2];
  const float* euw = (const float*)d_in[3];
  const float* edw = (const float*)d_in[4];
  const float* sgw = (const float*)d_in[5];
  const float* suw = (const float*)d_in[6];
  const float* sdw = (const float*)d_in[7];
  float* out = (float*)d_out;

  char* ws = (char*)d_ws;
  size_t off = 0;
  auto alloc = [&](size_t bytes) -> void* {
    void* p = ws + off; off = (off + bytes + 255) & ~(size_t)255; return p;
  };
  const size_t EW = (size_t)NEXP * HDIM * CDIM;   // 22,544,384
  const size_t SW = (size_t)HDIM * CDIM;          // 2,818,048
  bf16_t* xb    = (bf16_t*)alloc((size_t)N_TOK * CDIM * 2);
  bf16_t* egw_b = (bf16_t*)alloc(EW * 2);
  bf16_t* euw_b = (bf16_t*)alloc(EW * 2);
  bf16_t* edw_b = (bf16_t*)alloc(EW * 2);
  bf16_t* sgw_b = (bf16_t*)alloc(SW * 2);
  bf16_t* suw_b = (bf16_t*)alloc(SW * 2);
  bf16_t* sdw_b = (bf16_t*)alloc(SW * 2);
  bf16_t* h     = (bf16_t*)alloc((size_t)(3 * N_TOK + 256) * HDIM * 2);
  float*  eo    = (float*)alloc((size_t)2 * N_TOK * CDIM * 4);
  int*    ctrl  = (int*)alloc(256);
  int* cnts = ctrl; int* offs = ctrl + 8;
  int*   top_i    = (int*)alloc((size_t)N_TOK * 2 * 4);
  float* top_w    = (float*)alloc((size_t)N_TOK * 2 * 4);
  int*   pair_pos = (int*)alloc((size_t)N_TOK * 2 * 4);
  int*   rowlist  = (int*)alloc((size_t)2 * N_TOK * 4);
  float* wlist    = (float*)alloc((size_t)2 * N_TOK * 4);
  float* probs_tok = (float*)alloc((size_t)N_TOK * NEXP * 4);
  int*   pcnt     = (int*)alloc(16 * NEXP * 4);
  float* psum     = (float*)alloc(16 * NEXP * 4);

  // fused gu-side weight precast (egw, euw, sgw, suw) + gating, one launch
  CastG cg;
  cg.src[0] = egw; cg.dst[0] = egw_b;
  cg.src[1] = euw; cg.dst[1] = euw_b;
  cg.src[2] = sgw; cg.dst[2] = sgw_b;
  cg.src[3] = suw; cg.dst[3] = suw_b;
  int ew_blk = (int)(EW / 1024), sw_blk = (int)(SW / 1024);
  cg.start[0] = 0;
  cg.start[1] = ew_blk;
  cg.start[2] = 2 * ew_blk;
  cg.start[3] = 2 * ew_blk + sw_blk;
  cg.start[4] = 2 * ew_blk + 2 * sw_blk;
  cg.x = x; cg.gw = gw;
  cg.top_i = top_i; cg.top_w = top_w; cg.probs_tok = probs_tok; cg.xb = xb;
  moe_cast_gate<<<cg.start[4] + N_TOK / 4, 256, 0, stream>>>(cg);

  // parallel control: 16-block reduce, then 16-block deterministic scatter
  moe_reduce16<<<16, 256, 0, stream>>>(probs_tok, top_i, pcnt, psum);
  moe_scatter16<<<16, 256, 0, stream>>>(top_i, top_w, pcnt, psum, cnts, offs,
                                        rowlist, wlist, pair_pos,
                                        out + (size_t)N_TOK * CDIM);

  // gate+up: z = 8 routed + 1 shared + 1 down-weight-cast slice (overlapped)
  moe_gu<<<dim3(HDIM / 64, N_TOK / 128, NEXP + 2), 256, 0, stream>>>(
      xb, egw_b, euw_b, sgw_b, suw_b, h, rowlist, offs, cnts,
      edw, sdw, edw_b, sdw_b);
  // down: flattened grid, m fastest + XCD swizzle; routed -> eo, shared -> out
  moe_down<<<dim3((CDIM / 128) * (N_TOK / 128), 1, NEXP + 1), 256, 0, stream>>>(
      h, edw_b, sdw_b, out, eo, wlist, offs, cnts);
  // combine: out = shared + routed pair
  moe_combine<<<4096, 256, 0, stream>>>(out, eo, pair_pos);
}